// Round 3
// baseline (1152.198 us; speedup 1.0000x reference)
//
#include <hip/hip_runtime.h>
#include <stdint.h>

#define NN 50000
#define NE 1600000
#define FI 512
#define DD 512
#define NC 40
#define HW 1536   // h row width: [t | s1 | s2]

typedef __attribute__((ext_vector_type(8))) short short8;
typedef __attribute__((ext_vector_type(4))) float float4v;

static __device__ __forceinline__ unsigned short f2b(float f) {
    union { float f; unsigned int i; } v; v.f = f;
    unsigned int r = v.i + 0x7fffu + ((v.i >> 16) & 1u);
    return (unsigned short)(r >> 16);
}
static __device__ __forceinline__ float blo(unsigned int u) {
    union { unsigned int i; float f; } v; v.i = u << 16; return v.f;
}
static __device__ __forceinline__ float bhi(unsigned int u) {
    union { unsigned int i; float f; } v; v.i = u & 0xffff0000u; return v.f;
}
static __device__ __forceinline__ void async_copy16(void* lds, const void* g) {
    __builtin_amdgcn_global_load_lds((const __attribute__((address_space(1))) void*)g,
                                     (__attribute__((address_space(3))) void*)lds, 16, 0, 0);
}

// ---------------- input conversion: x (fp32) -> bf16, strided into hbuf cols [512,1024) ----------------
__global__ void convx_kernel(const float* __restrict__ x, unsigned short* __restrict__ dst) {
    int t = blockIdx.x * 256 + threadIdx.x;     // NN*64 threads, 8 elems each
    int r = t >> 6;
    int c = (t & 63) * 8;
    if (r >= NN) return;
    const float* xf = x + (size_t)r * 512 + c;
    float4 v0 = *(const float4*)(xf);
    float4 v1 = *(const float4*)(xf + 4);
    uint4 u;
    u.x = ((unsigned)f2b(v0.y) << 16) | f2b(v0.x);
    u.y = ((unsigned)f2b(v0.w) << 16) | f2b(v0.z);
    u.z = ((unsigned)f2b(v1.y) << 16) | f2b(v1.x);
    u.w = ((unsigned)f2b(v1.w) << 16) | f2b(v1.z);
    *(uint4*)(dst + (size_t)r * HW + c) = u;
}

// ---------------- CSR build ----------------
__global__ void count_kernel(const int* __restrict__ row, const int* __restrict__ col,
                             int* cnt_row, int* deg) {
    int e = blockIdx.x * 256 + threadIdx.x;
    if (e < NE) {
        atomicAdd(&cnt_row[row[e]], 1);
        atomicAdd(&deg[col[e]], 1);
    }
}

__global__ void dinv_kernel(const int* __restrict__ deg, float* __restrict__ dinv) {
    int i = blockIdx.x * 256 + threadIdx.x;
    if (i < NN) dinv[i] = rsqrtf((float)(deg[i] + 1));  // +1 self-loop
}

__global__ void scan_kernel(const int* __restrict__ cnt, int* __restrict__ rowptr,
                            int* __restrict__ cursor) {
    __shared__ int buf[1024];
    __shared__ int carry_s;
    int tid = threadIdx.x;
    if (tid == 0) carry_s = 0;
    __syncthreads();
    for (int base = 0; base < NN; base += 1024) {
        int i = base + tid;
        int v = (i < NN) ? cnt[i] : 0;
        buf[tid] = v;
        __syncthreads();
        int acc = v;
        for (int off = 1; off < 1024; off <<= 1) {
            int t = (tid >= off) ? buf[tid - off] : 0;
            __syncthreads();
            acc += t;
            buf[tid] = acc;
            __syncthreads();
        }
        int carry = carry_s;
        int excl = carry + acc - v;
        if (i < NN) { rowptr[i] = excl; cursor[i] = excl; }
        __syncthreads();
        if (tid == 1023) carry_s = carry + acc;
        __syncthreads();
    }
    if (tid == 0) rowptr[NN] = carry_s;
}

__global__ void scatter_kernel(const int* __restrict__ row, const int* __restrict__ col,
                               int* cursor, int* __restrict__ cols_out) {
    int e = blockIdx.x * 256 + threadIdx.x;
    if (e < NE) {
        int p = atomicAdd(&cursor[row[e]], 1);
        cols_out[p] = col[e];
    }
}

// ---------------- weight prep ----------------
__global__ void transpose_kernel(const float* __restrict__ w, unsigned short* __restrict__ wt) {
    int t = blockIdx.x * 256 + threadIdx.x;   // 512*512
    int n = t & 511, k = t >> 9;
    wt[n * 512 + k] = f2b(w[(size_t)k * 512 + n]);
}

// WcatT[n][k], n<48 (pad), k<1536 : combined final weight, transposed, bf16
__global__ void wcat_kernel(const float* __restrict__ w2, unsigned short* __restrict__ wct) {
    int t = blockIdx.x * 256 + threadIdx.x;   // 48*1536
    int k = t % HW, n = t / HW;
    float v = 0.f;
    if (n < NC) {
        if (k < 512)       v = w2[(size_t)k * NC + n] + w2[(size_t)(k + 512) * NC + n];
        else if (k < 1024) v = w2[(size_t)(k + 512) * NC + n] + w2[(size_t)(k + 1024) * NC + n];
        else               v = w2[(size_t)(k + 1024) * NC + n];
    }
    wct[n * HW + k] = f2b(v);
}

// ---------------- GEMM1: t = relu(x@W1 + b1) -> hbuf[:, 0:512] ----------------
// xb points at hbuf+512 (bf16 x, row stride HW)
__global__ __launch_bounds__(256) void gemm1_kernel(
    const unsigned short* __restrict__ xb, const unsigned short* __restrict__ w1t,
    const float* __restrict__ b1, unsigned short* __restrict__ hbuf) {
    __shared__ __align__(16) unsigned short As[128 * 32];
    __shared__ __align__(16) unsigned short Bs[128 * 32];
    const int tid = threadIdx.x;
    const int wave = tid >> 6, lane = tid & 63;
    const int q = lane >> 4, c = lane & 15;
    const int wm = wave & 1, wn = wave >> 1;
    const int m0 = blockIdx.x * 128, n0 = blockIdx.y * 128;

    float4v acc[4][4];
    for (int i = 0; i < 4; ++i)
        for (int j = 0; j < 4; ++j)
            acc[i][j] = (float4v){0.f, 0.f, 0.f, 0.f};

    for (int k0 = 0; k0 < FI; k0 += 32) {
        __syncthreads();
        #pragma unroll
        for (int h = 0; h < 2; ++h) {
            int chunk = h * 256 + wave * 64 + lane;
            int r = chunk >> 2, kc = chunk & 3;
            int gm = m0 + r; gm = gm < NN ? gm : NN - 1;
            async_copy16((char*)As + (size_t)(h * 256 + wave * 64) * 16,
                         xb + (size_t)gm * HW + k0 + kc * 8);
            async_copy16((char*)Bs + (size_t)(h * 256 + wave * 64) * 16,
                         w1t + (size_t)(n0 + r) * FI + k0 + kc * 8);
        }
        __syncthreads();
        short8 a[4], b[4];
        #pragma unroll
        for (int mi = 0; mi < 4; ++mi)
            a[mi] = *(const short8*)(As + ((wm * 64 + mi * 16 + c) * 32 + q * 8));
        #pragma unroll
        for (int ni = 0; ni < 4; ++ni)
            b[ni] = *(const short8*)(Bs + ((wn * 64 + ni * 16 + c) * 32 + q * 8));
        #pragma unroll
        for (int mi = 0; mi < 4; ++mi)
            #pragma unroll
            for (int ni = 0; ni < 4; ++ni)
                acc[mi][ni] = __builtin_amdgcn_mfma_f32_16x16x32_bf16(a[mi], b[ni], acc[mi][ni], 0, 0, 0);
    }
    #pragma unroll
    for (int ni = 0; ni < 4; ++ni) {
        int col = n0 + wn * 64 + ni * 16 + c;
        float bias = b1[col];
        #pragma unroll
        for (int mi = 0; mi < 4; ++mi) {
            int rbase = m0 + wm * 64 + mi * 16 + q * 4;
            #pragma unroll
            for (int r = 0; r < 4; ++r) {
                int row = rbase + r;
                if (row < NN) {
                    float v = acc[mi][ni][r] + bias;
                    hbuf[(size_t)row * HW + col] = f2b(v > 0.f ? v : 0.f);
                }
            }
        }
    }
}

// ---------------- SpMM: hbuf[:,seg_out] = A_norm @ hbuf[:,seg_in]  (one wave per row) ----------------
__global__ __launch_bounds__(256) void spmm_kernel(
    unsigned short* __restrict__ hbuf, const int* __restrict__ rowptr,
    const int* __restrict__ cols, const float* __restrict__ dinv,
    int seg_in, int seg_out) {
    int i = blockIdx.x * 4 + (threadIdx.x >> 6);
    if (i >= NN) return;
    int lane = threadIdx.x & 63;
    const float di = dinv[i];
    const unsigned short* bin = hbuf + seg_in + lane * 8;

    float a0, a1, a2, a3, a4, a5, a6, a7;
    {   // self-loop: dinv[i]^2 * t[i]
        uint4 u = *(const uint4*)(bin + (size_t)i * HW);
        float s = di * di;
        a0 = s * blo(u.x); a1 = s * bhi(u.x);
        a2 = s * blo(u.y); a3 = s * bhi(u.y);
        a4 = s * blo(u.z); a5 = s * bhi(u.z);
        a6 = s * blo(u.w); a7 = s * bhi(u.w);
    }
    int k = rowptr[i], e = rowptr[i + 1];
    int cn = (k < e) ? cols[k] : 0;
    while (k < e) {
        int cc = cn;
        ++k;
        cn = (k < e) ? cols[k] : 0;          // prefetch next col index
        float v = di * dinv[cc];
        uint4 u = *(const uint4*)(bin + (size_t)cc * HW);
        a0 += v * blo(u.x); a1 += v * bhi(u.x);
        a2 += v * blo(u.y); a3 += v * bhi(u.y);
        a4 += v * blo(u.z); a5 += v * bhi(u.z);
        a6 += v * blo(u.w); a7 += v * bhi(u.w);
    }
    uint4 o;
    o.x = ((unsigned int)f2b(a1) << 16) | f2b(a0);
    o.y = ((unsigned int)f2b(a3) << 16) | f2b(a2);
    o.z = ((unsigned int)f2b(a5) << 16) | f2b(a4);
    o.w = ((unsigned int)f2b(a7) << 16) | f2b(a6);
    *(uint4*)(hbuf + seg_out + lane * 8 + (size_t)i * HW) = o;
}

// ---------------- GEMM2 + log_softmax (fp32 output) ----------------
__global__ __launch_bounds__(256) void gemm2_kernel(
    const unsigned short* __restrict__ hbuf, const unsigned short* __restrict__ wct,
    const float* __restrict__ b2p, float* __restrict__ out) {
    int wave = threadIdx.x >> 6, lane = threadIdx.x & 63;
    int q = lane >> 4, c = lane & 15;
    int row0 = blockIdx.x * 64 + wave * 16;
    int ra = row0 + c; ra = ra < NN ? ra : NN - 1;
    const unsigned short* ap  = hbuf + (size_t)ra * HW + q * 8;
    const unsigned short* bp0 = wct + (size_t)(c)      * HW + q * 8;
    const unsigned short* bp1 = wct + (size_t)(16 + c) * HW + q * 8;
    const unsigned short* bp2 = wct + (size_t)(32 + c) * HW + q * 8;

    float4v A0 = {0.f,0.f,0.f,0.f}, A1 = {0.f,0.f,0.f,0.f}, A2 = {0.f,0.f,0.f,0.f};
    #pragma unroll 4
    for (int k0 = 0; k0 < HW; k0 += 32) {
        short8 a  = *(const short8*)(ap + k0);
        short8 b0 = *(const short8*)(bp0 + k0);
        short8 b1 = *(const short8*)(bp1 + k0);
        short8 b2 = *(const short8*)(bp2 + k0);
        A0 = __builtin_amdgcn_mfma_f32_16x16x32_bf16(a, b0, A0, 0, 0, 0);
        A1 = __builtin_amdgcn_mfma_f32_16x16x32_bf16(a, b1, A1, 0, 0, 0);
        A2 = __builtin_amdgcn_mfma_f32_16x16x32_bf16(a, b2, A2, 0, 0, 0);
    }
    float bias0 = b2p[c];
    float bias1 = b2p[16 + c];
    float bias2 = (c < 8) ? b2p[32 + c] : 0.f;
    #pragma unroll
    for (int r = 0; r < 4; ++r) {
        float v0 = A0[r] + bias0;
        float v1 = A1[r] + bias1;
        float v2 = (c < 8) ? (A2[r] + bias2) : -1e30f;
        float mx = fmaxf(fmaxf(v0, v1), v2);
        #pragma unroll
        for (int d = 1; d < 16; d <<= 1) mx = fmaxf(mx, __shfl_xor(mx, d, 64));
        float s = __expf(v0 - mx) + __expf(v1 - mx) + ((c < 8) ? __expf(v2 - mx) : 0.f);
        #pragma unroll
        for (int d = 1; d < 16; d <<= 1) s += __shfl_xor(s, d, 64);
        float lse = mx + __logf(s);
        int rowg = row0 + q * 4 + r;
        if (rowg < NN) {
            out[(size_t)rowg * NC + c]      = v0 - lse;
            out[(size_t)rowg * NC + 16 + c] = v1 - lse;
            if (c < 8) out[(size_t)rowg * NC + 32 + c] = v2 - lse;
        }
    }
}

extern "C" void kernel_launch(void* const* d_in, const int* in_sizes, int n_in,
                              void* d_out, int out_size, void* d_ws, size_t ws_size,
                              hipStream_t stream) {
    const float* x  = (const float*)d_in[0];
    const int*   er = (const int*)d_in[1];
    const int*   ec = (const int*)d_in[2];
    const float* W1 = (const float*)d_in[3];
    const float* b1 = (const float*)d_in[4];
    const float* W2 = (const float*)d_in[5];
    const float* b2 = (const float*)d_in[6];
    float* out = (float*)d_out;

    char* p = (char*)d_ws;
    auto alloc = [&](size_t bytes) { char* r = p; p += (bytes + 255) & ~((size_t)255); return r; };
    int*   cnt_row = (int*)  alloc((size_t)NN * 4);
    int*   deg     = (int*)  alloc((size_t)NN * 4);
    int*   rowptr  = (int*)  alloc((size_t)(NN + 1) * 4);
    int*   cursor  = (int*)  alloc((size_t)NN * 4);
    float* dinv    = (float*)alloc((size_t)NN * 4);
    int*   colss   = (int*)  alloc((size_t)NE * 4);
    unsigned short* w1t  = (unsigned short*)alloc((size_t)512 * 512 * 2);
    unsigned short* wct  = (unsigned short*)alloc((size_t)48 * HW * 2);
    unsigned short* hbuf = (unsigned short*)alloc((size_t)NN * HW * 2);
    unsigned short* xb   = hbuf + 512;   // bf16 x lives in the (dead until spmm1) s1 segment

    hipMemsetAsync(cnt_row, 0, (size_t)NN * 4, stream);
    hipMemsetAsync(deg, 0, (size_t)NN * 4, stream);

    convx_kernel<<<(NN * 64 + 255) / 256, 256, 0, stream>>>(x, xb);
    transpose_kernel<<<(512 * 512) / 256, 256, 0, stream>>>(W1, w1t);
    wcat_kernel<<<(48 * HW) / 256, 256, 0, stream>>>(W2, wct);

    count_kernel<<<(NE + 255) / 256, 256, 0, stream>>>(er, ec, cnt_row, deg);
    dinv_kernel<<<(NN + 255) / 256, 256, 0, stream>>>(deg, dinv);
    scan_kernel<<<1, 1024, 0, stream>>>(cnt_row, rowptr, cursor);
    scatter_kernel<<<(NE + 255) / 256, 256, 0, stream>>>(er, ec, cursor, colss);

    gemm1_kernel<<<dim3((NN + 127) / 128, DD / 128), 256, 0, stream>>>(xb, w1t, b1, hbuf);
    spmm_kernel<<<(NN + 3) / 4, 256, 0, stream>>>(hbuf, rowptr, colss, dinv, 0, 512);
    spmm_kernel<<<(NN + 3) / 4, 256, 0, stream>>>(hbuf, rowptr, colss, dinv, 512, 1024);
    gemm2_kernel<<<(NN + 63) / 64, 256, 0, stream>>>(hbuf, wct, b2, out);
}

// Round 4
// 1041.919 us; speedup vs baseline: 1.1058x; 1.1058x over previous
//
#include <hip/hip_runtime.h>
#include <stdint.h>

#define NN 50000
#define NE 1600000
#define FI 512
#define DD 512
#define NC 40
#define HW 1536   // h row width: [t | s1 | s2]
#define SCAN_NB 49  // ceil(NN/1024)

typedef __attribute__((ext_vector_type(8))) short short8;
typedef __attribute__((ext_vector_type(4))) float float4v;

static __device__ __forceinline__ unsigned short f2b(float f) {
    union { float f; unsigned int i; } v; v.f = f;
    unsigned int r = v.i + 0x7fffu + ((v.i >> 16) & 1u);
    return (unsigned short)(r >> 16);
}
static __device__ __forceinline__ float blo(unsigned int u) {
    union { unsigned int i; float f; } v; v.i = u << 16; return v.f;
}
static __device__ __forceinline__ float bhi(unsigned int u) {
    union { unsigned int i; float f; } v; v.i = u & 0xffff0000u; return v.f;
}
static __device__ __forceinline__ void async_copy16(void* lds, const void* g) {
    __builtin_amdgcn_global_load_lds((const __attribute__((address_space(1))) void*)g,
                                     (__attribute__((address_space(3))) void*)lds, 16, 0, 0);
}

// ---------------- input conversion: x (fp32) -> bf16, strided into hbuf cols [512,1024) ----------------
__global__ void convx_kernel(const float* __restrict__ x, unsigned short* __restrict__ dst) {
    int t = blockIdx.x * 256 + threadIdx.x;     // NN*64 threads, 8 elems each
    int r = t >> 6;
    int c = (t & 63) * 8;
    if (r >= NN) return;
    const float* xf = x + (size_t)r * 512 + c;
    float4 v0 = *(const float4*)(xf);
    float4 v1 = *(const float4*)(xf + 4);
    uint4 u;
    u.x = ((unsigned)f2b(v0.y) << 16) | f2b(v0.x);
    u.y = ((unsigned)f2b(v0.w) << 16) | f2b(v0.z);
    u.z = ((unsigned)f2b(v1.y) << 16) | f2b(v1.x);
    u.w = ((unsigned)f2b(v1.w) << 16) | f2b(v1.z);
    *(uint4*)(dst + (size_t)r * HW + c) = u;
}

// ---------------- CSR build ----------------
__global__ void count_kernel(const int* __restrict__ row, const int* __restrict__ col,
                             int* cnt_row, int* deg) {
    int e = blockIdx.x * 256 + threadIdx.x;
    if (e < NE) {
        atomicAdd(&cnt_row[row[e]], 1);
        atomicAdd(&deg[col[e]], 1);
    }
}

__global__ void dinv_kernel(const int* __restrict__ deg, float* __restrict__ dinv) {
    int i = blockIdx.x * 256 + threadIdx.x;
    if (i < NN) dinv[i] = rsqrtf((float)(deg[i] + 1));  // +1 self-loop
}

// ---- parallel 3-phase exclusive scan of cnt_row -> rowptr (+cursor copy) ----
__global__ __launch_bounds__(1024) void scan1_kernel(const int* __restrict__ cnt,
                                                     int* __restrict__ excl, int* __restrict__ bsum) {
    __shared__ int buf[1024];
    int tid = threadIdx.x, gid = blockIdx.x * 1024 + tid;
    int v = (gid < NN) ? cnt[gid] : 0;
    buf[tid] = v;
    __syncthreads();
    int acc = v;
    for (int off = 1; off < 1024; off <<= 1) {
        int t = (tid >= off) ? buf[tid - off] : 0;
        __syncthreads();
        acc += t;
        buf[tid] = acc;
        __syncthreads();
    }
    if (gid < NN) excl[gid] = acc - v;       // block-local exclusive
    if (tid == 1023) bsum[blockIdx.x] = acc; // block total
}

__global__ void scan2_kernel(const int* __restrict__ bsum, int* __restrict__ boff) {
    int tid = threadIdx.x;  // one wave of 64, SCAN_NB=49
    int orig = (tid < SCAN_NB) ? bsum[tid] : 0;
    int v = orig;
    #pragma unroll
    for (int off = 1; off < 64; off <<= 1) {
        int t = __shfl_up(v, off, 64);
        if (tid >= off) v += t;
    }
    if (tid < SCAN_NB) boff[tid] = v - orig;  // exclusive block offset
}

__global__ void scan3_kernel(int* __restrict__ rowptr, const int* __restrict__ boff,
                             int* __restrict__ cursor) {
    int gid = blockIdx.x * 256 + threadIdx.x;
    if (gid < NN) {
        int r = rowptr[gid] + boff[gid >> 10];
        rowptr[gid] = r;
        cursor[gid] = r;
    }
    if (gid == 0) rowptr[NN] = NE;
}

__global__ void scatter_kernel(const int* __restrict__ row, const int* __restrict__ col,
                               int* cursor, int* __restrict__ cols_out) {
    int e = blockIdx.x * 256 + threadIdx.x;
    if (e < NE) {
        int p = atomicAdd(&cursor[row[e]], 1);
        cols_out[p] = col[e];
    }
}

// ---------------- weight prep ----------------
__global__ void transpose_kernel(const float* __restrict__ w, unsigned short* __restrict__ wt) {
    int t = blockIdx.x * 256 + threadIdx.x;   // 512*512
    int n = t & 511, k = t >> 9;
    wt[n * 512 + k] = f2b(w[(size_t)k * 512 + n]);
}

// WcatT[n][k], n<48 (pad), k<1536 : combined final weight, transposed, bf16
__global__ void wcat_kernel(const float* __restrict__ w2, unsigned short* __restrict__ wct) {
    int t = blockIdx.x * 256 + threadIdx.x;   // 48*1536
    int k = t % HW, n = t / HW;
    float v = 0.f;
    if (n < NC) {
        if (k < 512)       v = w2[(size_t)k * NC + n] + w2[(size_t)(k + 512) * NC + n];
        else if (k < 1024) v = w2[(size_t)(k + 512) * NC + n] + w2[(size_t)(k + 1024) * NC + n];
        else               v = w2[(size_t)(k + 1024) * NC + n];
    }
    wct[n * HW + k] = f2b(v);
}

// ---------------- GEMM1: t = relu(x@W1 + b1) -> hbuf[:, 0:512] ----------------
__global__ __launch_bounds__(256) void gemm1_kernel(
    const unsigned short* __restrict__ xb, const unsigned short* __restrict__ w1t,
    const float* __restrict__ b1, unsigned short* __restrict__ hbuf) {
    __shared__ __align__(16) unsigned short As[128 * 32];
    __shared__ __align__(16) unsigned short Bs[128 * 32];
    const int tid = threadIdx.x;
    const int wave = tid >> 6, lane = tid & 63;
    const int q = lane >> 4, c = lane & 15;
    const int wm = wave & 1, wn = wave >> 1;
    const int m0 = blockIdx.x * 128, n0 = blockIdx.y * 128;

    float4v acc[4][4];
    for (int i = 0; i < 4; ++i)
        for (int j = 0; j < 4; ++j)
            acc[i][j] = (float4v){0.f, 0.f, 0.f, 0.f};

    for (int k0 = 0; k0 < FI; k0 += 32) {
        __syncthreads();
        #pragma unroll
        for (int h = 0; h < 2; ++h) {
            int chunk = h * 256 + wave * 64 + lane;
            int r = chunk >> 2, kc = chunk & 3;
            int gm = m0 + r; gm = gm < NN ? gm : NN - 1;
            async_copy16((char*)As + (size_t)(h * 256 + wave * 64) * 16,
                         xb + (size_t)gm * HW + k0 + kc * 8);
            async_copy16((char*)Bs + (size_t)(h * 256 + wave * 64) * 16,
                         w1t + (size_t)(n0 + r) * FI + k0 + kc * 8);
        }
        __syncthreads();
        short8 a[4], b[4];
        #pragma unroll
        for (int mi = 0; mi < 4; ++mi)
            a[mi] = *(const short8*)(As + ((wm * 64 + mi * 16 + c) * 32 + q * 8));
        #pragma unroll
        for (int ni = 0; ni < 4; ++ni)
            b[ni] = *(const short8*)(Bs + ((wn * 64 + ni * 16 + c) * 32 + q * 8));
        #pragma unroll
        for (int mi = 0; mi < 4; ++mi)
            #pragma unroll
            for (int ni = 0; ni < 4; ++ni)
                acc[mi][ni] = __builtin_amdgcn_mfma_f32_16x16x32_bf16(a[mi], b[ni], acc[mi][ni], 0, 0, 0);
    }
    #pragma unroll
    for (int ni = 0; ni < 4; ++ni) {
        int col = n0 + wn * 64 + ni * 16 + c;
        float bias = b1[col];
        #pragma unroll
        for (int mi = 0; mi < 4; ++mi) {
            int rbase = m0 + wm * 64 + mi * 16 + q * 4;
            #pragma unroll
            for (int r = 0; r < 4; ++r) {
                int row = rbase + r;
                if (row < NN) {
                    float v = acc[mi][ni][r] + bias;
                    hbuf[(size_t)row * HW + col] = f2b(v > 0.f ? v : 0.f);
                }
            }
        }
    }
}

// ---------------- SpMM: hbuf[:,seg_out] = A_norm @ hbuf[:,seg_in]  (one wave per row) ----------------
// Unrolled x8: 8 independent gathers in flight per wave (latency -> BW bound).
#define ACC8(u, vv)                              \
    a0 += (vv) * blo(u.x); a1 += (vv) * bhi(u.x); \
    a2 += (vv) * blo(u.y); a3 += (vv) * bhi(u.y); \
    a4 += (vv) * blo(u.z); a5 += (vv) * bhi(u.z); \
    a6 += (vv) * blo(u.w); a7 += (vv) * bhi(u.w);

__global__ __launch_bounds__(256) void spmm_kernel(
    unsigned short* __restrict__ hbuf, const int* __restrict__ rowptr,
    const int* __restrict__ cols, const float* __restrict__ dinv,
    int seg_in, int seg_out) {
    int i = blockIdx.x * 4 + (threadIdx.x >> 6);
    if (i >= NN) return;
    int lane = threadIdx.x & 63;
    const float di = dinv[i];
    const unsigned short* bin = hbuf + seg_in + lane * 8;

    float a0, a1, a2, a3, a4, a5, a6, a7;
    {   // self-loop: dinv[i]^2 * t[i]
        uint4 u = *(const uint4*)(bin + (size_t)i * HW);
        float s = di * di;
        a0 = s * blo(u.x); a1 = s * bhi(u.x);
        a2 = s * blo(u.y); a3 = s * bhi(u.y);
        a4 = s * blo(u.z); a5 = s * bhi(u.z);
        a6 = s * blo(u.w); a7 = s * bhi(u.w);
    }
    int k = rowptr[i], e = rowptr[i + 1];
    for (; k + 8 <= e; k += 8) {
        int c0 = cols[k + 0], c1 = cols[k + 1], c2 = cols[k + 2], c3 = cols[k + 3];
        int c4 = cols[k + 4], c5 = cols[k + 5], c6 = cols[k + 6], c7 = cols[k + 7];
        uint4 u0 = *(const uint4*)(bin + (size_t)c0 * HW);
        uint4 u1 = *(const uint4*)(bin + (size_t)c1 * HW);
        uint4 u2 = *(const uint4*)(bin + (size_t)c2 * HW);
        uint4 u3 = *(const uint4*)(bin + (size_t)c3 * HW);
        uint4 u4 = *(const uint4*)(bin + (size_t)c4 * HW);
        uint4 u5 = *(const uint4*)(bin + (size_t)c5 * HW);
        uint4 u6 = *(const uint4*)(bin + (size_t)c6 * HW);
        uint4 u7 = *(const uint4*)(bin + (size_t)c7 * HW);
        float v0 = di * dinv[c0], v1 = di * dinv[c1], v2 = di * dinv[c2], v3 = di * dinv[c3];
        float v4 = di * dinv[c4], v5 = di * dinv[c5], v6 = di * dinv[c6], v7 = di * dinv[c7];
        ACC8(u0, v0) ACC8(u1, v1) ACC8(u2, v2) ACC8(u3, v3)
        ACC8(u4, v4) ACC8(u5, v5) ACC8(u6, v6) ACC8(u7, v7)
    }
    for (; k < e; ++k) {
        int cc = cols[k];
        float v = di * dinv[cc];
        uint4 u = *(const uint4*)(bin + (size_t)cc * HW);
        ACC8(u, v)
    }
    uint4 o;
    o.x = ((unsigned int)f2b(a1) << 16) | f2b(a0);
    o.y = ((unsigned int)f2b(a3) << 16) | f2b(a2);
    o.z = ((unsigned int)f2b(a5) << 16) | f2b(a4);
    o.w = ((unsigned int)f2b(a7) << 16) | f2b(a6);
    *(uint4*)(hbuf + seg_out + lane * 8 + (size_t)i * HW) = o;
}

// ---------------- GEMM2 + log_softmax (fp32 output) ----------------
__global__ __launch_bounds__(256) void gemm2_kernel(
    const unsigned short* __restrict__ hbuf, const unsigned short* __restrict__ wct,
    const float* __restrict__ b2p, float* __restrict__ out) {
    int wave = threadIdx.x >> 6, lane = threadIdx.x & 63;
    int q = lane >> 4, c = lane & 15;
    int row0 = blockIdx.x * 64 + wave * 16;
    int ra = row0 + c; ra = ra < NN ? ra : NN - 1;
    const unsigned short* ap  = hbuf + (size_t)ra * HW + q * 8;
    const unsigned short* bp0 = wct + (size_t)(c)      * HW + q * 8;
    const unsigned short* bp1 = wct + (size_t)(16 + c) * HW + q * 8;
    const unsigned short* bp2 = wct + (size_t)(32 + c) * HW + q * 8;

    float4v A0 = {0.f,0.f,0.f,0.f}, A1 = {0.f,0.f,0.f,0.f}, A2 = {0.f,0.f,0.f,0.f};
    #pragma unroll 4
    for (int k0 = 0; k0 < HW; k0 += 32) {
        short8 a  = *(const short8*)(ap + k0);
        short8 b0 = *(const short8*)(bp0 + k0);
        short8 b1 = *(const short8*)(bp1 + k0);
        short8 b2 = *(const short8*)(bp2 + k0);
        A0 = __builtin_amdgcn_mfma_f32_16x16x32_bf16(a, b0, A0, 0, 0, 0);
        A1 = __builtin_amdgcn_mfma_f32_16x16x32_bf16(a, b1, A1, 0, 0, 0);
        A2 = __builtin_amdgcn_mfma_f32_16x16x32_bf16(a, b2, A2, 0, 0, 0);
    }
    float bias0 = b2p[c];
    float bias1 = b2p[16 + c];
    float bias2 = (c < 8) ? b2p[32 + c] : 0.f;
    #pragma unroll
    for (int r = 0; r < 4; ++r) {
        float v0 = A0[r] + bias0;
        float v1 = A1[r] + bias1;
        float v2 = (c < 8) ? (A2[r] + bias2) : -1e30f;
        float mx = fmaxf(fmaxf(v0, v1), v2);
        #pragma unroll
        for (int d = 1; d < 16; d <<= 1) mx = fmaxf(mx, __shfl_xor(mx, d, 64));
        float s = __expf(v0 - mx) + __expf(v1 - mx) + ((c < 8) ? __expf(v2 - mx) : 0.f);
        #pragma unroll
        for (int d = 1; d < 16; d <<= 1) s += __shfl_xor(s, d, 64);
        float lse = mx + __logf(s);
        int rowg = row0 + q * 4 + r;
        if (rowg < NN) {
            out[(size_t)rowg * NC + c]      = v0 - lse;
            out[(size_t)rowg * NC + 16 + c] = v1 - lse;
            if (c < 8) out[(size_t)rowg * NC + 32 + c] = v2 - lse;
        }
    }
}

extern "C" void kernel_launch(void* const* d_in, const int* in_sizes, int n_in,
                              void* d_out, int out_size, void* d_ws, size_t ws_size,
                              hipStream_t stream) {
    const float* x  = (const float*)d_in[0];
    const int*   er = (const int*)d_in[1];
    const int*   ec = (const int*)d_in[2];
    const float* W1 = (const float*)d_in[3];
    const float* b1 = (const float*)d_in[4];
    const float* W2 = (const float*)d_in[5];
    const float* b2 = (const float*)d_in[6];
    float* out = (float*)d_out;

    char* p = (char*)d_ws;
    auto alloc = [&](size_t bytes) { char* r = p; p += (bytes + 255) & ~((size_t)255); return r; };
    int*   cnt_row = (int*)  alloc((size_t)NN * 4);
    int*   deg     = (int*)  alloc((size_t)NN * 4);
    int*   rowptr  = (int*)  alloc((size_t)(NN + 1) * 4);
    int*   cursor  = (int*)  alloc((size_t)NN * 4);
    float* dinv    = (float*)alloc((size_t)NN * 4);
    int*   bsum    = (int*)  alloc((size_t)SCAN_NB * 4);
    int*   boff    = (int*)  alloc((size_t)SCAN_NB * 4);
    int*   colss   = (int*)  alloc((size_t)NE * 4);
    unsigned short* w1t  = (unsigned short*)alloc((size_t)512 * 512 * 2);
    unsigned short* wct  = (unsigned short*)alloc((size_t)48 * HW * 2);
    unsigned short* hbuf = (unsigned short*)alloc((size_t)NN * HW * 2);
    unsigned short* xb   = hbuf + 512;   // bf16 x lives in the (dead until spmm1) s1 segment

    hipMemsetAsync(cnt_row, 0, (size_t)NN * 4, stream);
    hipMemsetAsync(deg, 0, (size_t)NN * 4, stream);

    convx_kernel<<<(NN * 64 + 255) / 256, 256, 0, stream>>>(x, xb);
    transpose_kernel<<<(512 * 512) / 256, 256, 0, stream>>>(W1, w1t);
    wcat_kernel<<<(48 * HW) / 256, 256, 0, stream>>>(W2, wct);

    count_kernel<<<(NE + 255) / 256, 256, 0, stream>>>(er, ec, cnt_row, deg);
    dinv_kernel<<<(NN + 255) / 256, 256, 0, stream>>>(deg, dinv);
    scan1_kernel<<<SCAN_NB, 1024, 0, stream>>>(cnt_row, rowptr, bsum);
    scan2_kernel<<<1, 64, 0, stream>>>(bsum, boff);
    scan3_kernel<<<(NN + 255) / 256, 256, 0, stream>>>(rowptr, boff, cursor);
    scatter_kernel<<<(NE + 255) / 256, 256, 0, stream>>>(er, ec, cursor, colss);

    gemm1_kernel<<<dim3((NN + 127) / 128, DD / 128), 256, 0, stream>>>(xb, w1t, b1, hbuf);
    spmm_kernel<<<(NN + 3) / 4, 256, 0, stream>>>(hbuf, rowptr, colss, dinv, 0, 512);
    spmm_kernel<<<(NN + 3) / 4, 256, 0, stream>>>(hbuf, rowptr, colss, dinv, 512, 1024);
    gemm2_kernel<<<(NN + 63) / 64, 256, 0, stream>>>(hbuf, wct, b2, out);
}

// Round 5
// 950.220 us; speedup vs baseline: 1.2126x; 1.0965x over previous
//
#include <hip/hip_runtime.h>
#include <stdint.h>

#define NN 50000
#define NE 1600000
#define FI 512
#define DD 512
#define NC 40
#define HW 1536
#define SCAN_NB 49  // ceil(NN/1024)

typedef __attribute__((ext_vector_type(8))) short short8;
typedef __attribute__((ext_vector_type(4))) float float4v;

static __device__ __forceinline__ unsigned short f2b(float f) {
    union { float f; unsigned int i; } v; v.f = f;
    unsigned int r = v.i + 0x7fffu + ((v.i >> 16) & 1u);
    return (unsigned short)(r >> 16);
}
static __device__ __forceinline__ float blo(unsigned int u) {
    union { unsigned int i; float f; } v; v.i = u << 16; return v.f;
}
static __device__ __forceinline__ float bhi(unsigned int u) {
    union { unsigned int i; float f; } v; v.i = u & 0xffff0000u; return v.f;
}
static __device__ __forceinline__ void async_copy16(void* lds, const void* g) {
    __builtin_amdgcn_global_load_lds((const __attribute__((address_space(1))) void*)g,
                                     (__attribute__((address_space(3))) void*)lds, 16, 0, 0);
}

// ---------------- x (fp32) -> bf16 dense [NN,512] ----------------
__global__ void convx_kernel(const float* __restrict__ x, unsigned short* __restrict__ dst) {
    int t = blockIdx.x * 256 + threadIdx.x;     // NN*64 threads, 8 elems each
    if (t >= NN * 64) return;
    const float* xf = x + (size_t)t * 8;
    float4 v0 = *(const float4*)(xf);
    float4 v1 = *(const float4*)(xf + 4);
    uint4 u;
    u.x = ((unsigned)f2b(v0.y) << 16) | f2b(v0.x);
    u.y = ((unsigned)f2b(v0.w) << 16) | f2b(v0.z);
    u.z = ((unsigned)f2b(v1.y) << 16) | f2b(v1.x);
    u.w = ((unsigned)f2b(v1.w) << 16) | f2b(v1.z);
    *(uint4*)(dst + (size_t)t * 8) = u;
}

// ---------------- CSR build ----------------
// rank[e] = this edge's arrival order within its row; deg = in-degree (col)
__global__ void count_kernel(const int* __restrict__ row, const int* __restrict__ col,
                             int* cnt_row, int* deg, int* __restrict__ rank) {
    int e = blockIdx.x * 256 + threadIdx.x;
    if (e < NE) {
        rank[e] = atomicAdd(&cnt_row[row[e]], 1);
        atomicAdd(&deg[col[e]], 1);
    }
}

__global__ __launch_bounds__(1024) void scan1_kernel(const int* __restrict__ cnt,
                                                     int* __restrict__ excl, int* __restrict__ bsum) {
    __shared__ int buf[1024];
    int tid = threadIdx.x, gid = blockIdx.x * 1024 + tid;
    int v = (gid < NN) ? cnt[gid] : 0;
    buf[tid] = v;
    __syncthreads();
    int acc = v;
    for (int off = 1; off < 1024; off <<= 1) {
        int t = (tid >= off) ? buf[tid - off] : 0;
        __syncthreads();
        acc += t;
        buf[tid] = acc;
        __syncthreads();
    }
    if (gid < NN) excl[gid] = acc - v;
    if (tid == 1023) bsum[blockIdx.x] = acc;
}

__global__ void scan2_kernel(const int* __restrict__ bsum, int* __restrict__ boff) {
    int tid = threadIdx.x;
    int orig = (tid < SCAN_NB) ? bsum[tid] : 0;
    int v = orig;
    #pragma unroll
    for (int off = 1; off < 64; off <<= 1) {
        int t = __shfl_up(v, off, 64);
        if (tid >= off) v += t;
    }
    if (tid < SCAN_NB) boff[tid] = v - orig;
}

// finalize rowptr + compute dinv (fused)
__global__ void scan3_kernel(int* __restrict__ rowptr, const int* __restrict__ boff,
                             const int* __restrict__ deg, float* __restrict__ dinv) {
    int gid = blockIdx.x * 256 + threadIdx.x;
    if (gid < NN) {
        rowptr[gid] += boff[gid >> 10];
        dinv[gid] = rsqrtf((float)(deg[gid] + 1));
    }
    if (gid == 0) rowptr[NN] = NE;
}

// atomic-free placement using precomputed rank
__global__ void scatter_kernel(const int* __restrict__ row, const int* __restrict__ col,
                               const int* __restrict__ rowptr, const int* __restrict__ rank,
                               int* __restrict__ cols_out) {
    int e = blockIdx.x * 256 + threadIdx.x;
    if (e < NE) cols_out[rowptr[row[e]] + rank[e]] = col[e];
}

// ---------------- weight prep ----------------
__global__ void transpose_kernel(const float* __restrict__ w, unsigned short* __restrict__ wt) {
    int t = blockIdx.x * 256 + threadIdx.x;   // 512*512
    int n = t & 511, k = t >> 9;
    wt[n * 512 + k] = f2b(w[(size_t)k * 512 + n]);
}

// WcatT[n][k], k segments: [0,512)=t (W2[0:512]+W2[512:1024]), [512,1024)=s1, [1024,1536)=s2
__global__ void wcat_kernel(const float* __restrict__ w2, unsigned short* __restrict__ wct) {
    int t = blockIdx.x * 256 + threadIdx.x;   // 48*1536
    int k = t % HW, n = t / HW;
    float v = 0.f;
    if (n < NC) {
        if (k < 512)       v = w2[(size_t)k * NC + n] + w2[(size_t)(k + 512) * NC + n];
        else if (k < 1024) v = w2[(size_t)(k + 512) * NC + n] + w2[(size_t)(k + 1024) * NC + n];
        else               v = w2[(size_t)(k + 1024) * NC + n];
    }
    wct[n * HW + k] = f2b(v);
}

// ---------------- GEMM1: t = relu(x@W1 + b1), dense in/out ----------------
__global__ __launch_bounds__(256) void gemm1_kernel(
    const unsigned short* __restrict__ xb, const unsigned short* __restrict__ w1t,
    const float* __restrict__ b1, unsigned short* __restrict__ tbuf) {
    __shared__ __align__(16) unsigned short As[128 * 32];
    __shared__ __align__(16) unsigned short Bs[128 * 32];
    const int tid = threadIdx.x;
    const int wave = tid >> 6, lane = tid & 63;
    const int q = lane >> 4, c = lane & 15;
    const int wm = wave & 1, wn = wave >> 1;
    const int m0 = blockIdx.x * 128, n0 = blockIdx.y * 128;

    float4v acc[4][4];
    for (int i = 0; i < 4; ++i)
        for (int j = 0; j < 4; ++j)
            acc[i][j] = (float4v){0.f, 0.f, 0.f, 0.f};

    for (int k0 = 0; k0 < FI; k0 += 32) {
        __syncthreads();
        #pragma unroll
        for (int h = 0; h < 2; ++h) {
            int chunk = h * 256 + wave * 64 + lane;
            int r = chunk >> 2, kc = chunk & 3;
            int gm = m0 + r; gm = gm < NN ? gm : NN - 1;
            async_copy16((char*)As + (size_t)(h * 256 + wave * 64) * 16,
                         xb + (size_t)gm * FI + k0 + kc * 8);
            async_copy16((char*)Bs + (size_t)(h * 256 + wave * 64) * 16,
                         w1t + (size_t)(n0 + r) * FI + k0 + kc * 8);
        }
        __syncthreads();
        short8 a[4], b[4];
        #pragma unroll
        for (int mi = 0; mi < 4; ++mi)
            a[mi] = *(const short8*)(As + ((wm * 64 + mi * 16 + c) * 32 + q * 8));
        #pragma unroll
        for (int ni = 0; ni < 4; ++ni)
            b[ni] = *(const short8*)(Bs + ((wn * 64 + ni * 16 + c) * 32 + q * 8));
        #pragma unroll
        for (int mi = 0; mi < 4; ++mi)
            #pragma unroll
            for (int ni = 0; ni < 4; ++ni)
                acc[mi][ni] = __builtin_amdgcn_mfma_f32_16x16x32_bf16(a[mi], b[ni], acc[mi][ni], 0, 0, 0);
    }
    #pragma unroll
    for (int ni = 0; ni < 4; ++ni) {
        int col = n0 + wn * 64 + ni * 16 + c;
        float bias = b1[col];
        #pragma unroll
        for (int mi = 0; mi < 4; ++mi) {
            int rbase = m0 + wm * 64 + mi * 16 + q * 4;
            #pragma unroll
            for (int r = 0; r < 4; ++r) {
                int row = rbase + r;
                if (row < NN) {
                    float v = acc[mi][ni][r] + bias;
                    tbuf[(size_t)row * FI + col] = f2b(v > 0.f ? v : 0.f);
                }
            }
        }
    }
}

// ---------------- SpMM: dst = A_norm @ src, dense [NN,512] bf16 ----------------
#define ACC8(u, vv)                              \
    a0 += (vv) * blo(u.x); a1 += (vv) * bhi(u.x); \
    a2 += (vv) * blo(u.y); a3 += (vv) * bhi(u.y); \
    a4 += (vv) * blo(u.z); a5 += (vv) * bhi(u.z); \
    a6 += (vv) * blo(u.w); a7 += (vv) * bhi(u.w);

__global__ __launch_bounds__(256) void spmm_kernel(
    const unsigned short* __restrict__ src, unsigned short* __restrict__ dst,
    const int* __restrict__ rowptr, const int* __restrict__ cols,
    const float* __restrict__ dinv) {
    int i = blockIdx.x * 4 + (threadIdx.x >> 6);
    if (i >= NN) return;
    int lane = threadIdx.x & 63;
    const float di = dinv[i];
    const unsigned short* bin = src + lane * 8;

    float a0, a1, a2, a3, a4, a5, a6, a7;
    {   // self-loop
        uint4 u = *(const uint4*)(bin + (size_t)i * FI);
        float s = di * di;
        a0 = s * blo(u.x); a1 = s * bhi(u.x);
        a2 = s * blo(u.y); a3 = s * bhi(u.y);
        a4 = s * blo(u.z); a5 = s * bhi(u.z);
        a6 = s * blo(u.w); a7 = s * bhi(u.w);
    }
    int k = rowptr[i], e = rowptr[i + 1];
    for (; k + 8 <= e; k += 8) {
        // scalar index + weight loads first (lgkm path), then the 8 gathers (vm path)
        int c0 = cols[k + 0], c1 = cols[k + 1], c2 = cols[k + 2], c3 = cols[k + 3];
        int c4 = cols[k + 4], c5 = cols[k + 5], c6 = cols[k + 6], c7 = cols[k + 7];
        float w0 = dinv[c0], w1 = dinv[c1], w2 = dinv[c2], w3 = dinv[c3];
        float w4 = dinv[c4], w5 = dinv[c5], w6 = dinv[c6], w7 = dinv[c7];
        uint4 u0 = *(const uint4*)(bin + (size_t)c0 * FI);
        uint4 u1 = *(const uint4*)(bin + (size_t)c1 * FI);
        uint4 u2 = *(const uint4*)(bin + (size_t)c2 * FI);
        uint4 u3 = *(const uint4*)(bin + (size_t)c3 * FI);
        uint4 u4 = *(const uint4*)(bin + (size_t)c4 * FI);
        uint4 u5 = *(const uint4*)(bin + (size_t)c5 * FI);
        uint4 u6 = *(const uint4*)(bin + (size_t)c6 * FI);
        uint4 u7 = *(const uint4*)(bin + (size_t)c7 * FI);
        float v0 = di * w0, v1 = di * w1, v2 = di * w2, v3 = di * w3;
        float v4 = di * w4, v5 = di * w5, v6 = di * w6, v7 = di * w7;
        ACC8(u0, v0) ACC8(u1, v1) ACC8(u2, v2) ACC8(u3, v3)
        ACC8(u4, v4) ACC8(u5, v5) ACC8(u6, v6) ACC8(u7, v7)
    }
    for (; k < e; ++k) {
        int cc = cols[k];
        float v = di * dinv[cc];
        uint4 u = *(const uint4*)(bin + (size_t)cc * FI);
        ACC8(u, v)
    }
    uint4 o;
    o.x = ((unsigned int)f2b(a1) << 16) | f2b(a0);
    o.y = ((unsigned int)f2b(a3) << 16) | f2b(a2);
    o.z = ((unsigned int)f2b(a5) << 16) | f2b(a4);
    o.w = ((unsigned int)f2b(a7) << 16) | f2b(a6);
    *(uint4*)(dst + lane * 8 + (size_t)i * FI) = o;
}

// ---------------- GEMM2 + log_softmax (fp32 output), 3 dense A-segments ----------------
__global__ __launch_bounds__(256) void gemm2_kernel(
    const unsigned short* __restrict__ tb, const unsigned short* __restrict__ s1b,
    const unsigned short* __restrict__ s2b, const unsigned short* __restrict__ wct,
    const float* __restrict__ b2p, float* __restrict__ out) {
    int wave = threadIdx.x >> 6, lane = threadIdx.x & 63;
    int q = lane >> 4, c = lane & 15;
    int row0 = blockIdx.x * 64 + wave * 16;
    int ra = row0 + c; ra = ra < NN ? ra : NN - 1;
    const unsigned short* seg[3] = { tb + (size_t)ra * FI + q * 8,
                                     s1b + (size_t)ra * FI + q * 8,
                                     s2b + (size_t)ra * FI + q * 8 };
    const unsigned short* bp0 = wct + (size_t)(c)      * HW + q * 8;
    const unsigned short* bp1 = wct + (size_t)(16 + c) * HW + q * 8;
    const unsigned short* bp2 = wct + (size_t)(32 + c) * HW + q * 8;

    float4v A0 = {0.f,0.f,0.f,0.f}, A1 = {0.f,0.f,0.f,0.f}, A2 = {0.f,0.f,0.f,0.f};
    #pragma unroll
    for (int s = 0; s < 3; ++s) {
        const unsigned short* ap = seg[s];
        #pragma unroll 4
        for (int k0 = 0; k0 < 512; k0 += 32) {
            short8 a  = *(const short8*)(ap + k0);
            short8 b0 = *(const short8*)(bp0 + s * 512 + k0);
            short8 b1 = *(const short8*)(bp1 + s * 512 + k0);
            short8 b2 = *(const short8*)(bp2 + s * 512 + k0);
            A0 = __builtin_amdgcn_mfma_f32_16x16x32_bf16(a, b0, A0, 0, 0, 0);
            A1 = __builtin_amdgcn_mfma_f32_16x16x32_bf16(a, b1, A1, 0, 0, 0);
            A2 = __builtin_amdgcn_mfma_f32_16x16x32_bf16(a, b2, A2, 0, 0, 0);
        }
    }
    float bias0 = b2p[c];
    float bias1 = b2p[16 + c];
    float bias2 = (c < 8) ? b2p[32 + c] : 0.f;
    #pragma unroll
    for (int r = 0; r < 4; ++r) {
        float v0 = A0[r] + bias0;
        float v1 = A1[r] + bias1;
        float v2 = (c < 8) ? (A2[r] + bias2) : -1e30f;
        float mx = fmaxf(fmaxf(v0, v1), v2);
        #pragma unroll
        for (int d = 1; d < 16; d <<= 1) mx = fmaxf(mx, __shfl_xor(mx, d, 64));
        float s = __expf(v0 - mx) + __expf(v1 - mx) + ((c < 8) ? __expf(v2 - mx) : 0.f);
        #pragma unroll
        for (int d = 1; d < 16; d <<= 1) s += __shfl_xor(s, d, 64);
        float lse = mx + __logf(s);
        int rowg = row0 + q * 4 + r;
        if (rowg < NN) {
            out[(size_t)rowg * NC + c]      = v0 - lse;
            out[(size_t)rowg * NC + 16 + c] = v1 - lse;
            if (c < 8) out[(size_t)rowg * NC + 32 + c] = v2 - lse;
        }
    }
}

extern "C" void kernel_launch(void* const* d_in, const int* in_sizes, int n_in,
                              void* d_out, int out_size, void* d_ws, size_t ws_size,
                              hipStream_t stream) {
    const float* x  = (const float*)d_in[0];
    const int*   er = (const int*)d_in[1];
    const int*   ec = (const int*)d_in[2];
    const float* W1 = (const float*)d_in[3];
    const float* b1 = (const float*)d_in[4];
    const float* W2 = (const float*)d_in[5];
    const float* b2 = (const float*)d_in[6];
    float* out = (float*)d_out;

    char* p = (char*)d_ws;
    auto alloc = [&](size_t bytes) { char* r = p; p += (bytes + 255) & ~((size_t)255); return r; };
    int*   cnt_row = (int*)  alloc((size_t)NN * 4);
    int*   deg     = (int*)  alloc((size_t)NN * 4);
    int*   rowptr  = (int*)  alloc((size_t)(NN + 1) * 4);
    float* dinv    = (float*)alloc((size_t)NN * 4);
    int*   bsum    = (int*)  alloc((size_t)SCAN_NB * 4);
    int*   boff    = (int*)  alloc((size_t)SCAN_NB * 4);
    int*   rank    = (int*)  alloc((size_t)NE * 4);
    int*   colss   = (int*)  alloc((size_t)NE * 4);
    unsigned short* w1t  = (unsigned short*)alloc((size_t)512 * 512 * 2);
    unsigned short* wct  = (unsigned short*)alloc((size_t)48 * HW * 2);
    unsigned short* xb   = (unsigned short*)alloc((size_t)NN * FI * 2);
    unsigned short* tbuf = (unsigned short*)alloc((size_t)NN * FI * 2);
    unsigned short* s1b  = (unsigned short*)alloc((size_t)NN * FI * 2);
    unsigned short* s2b  = xb;   // xb is dead after gemm1; reuse for s2

    hipMemsetAsync(cnt_row, 0, (size_t)NN * 4, stream);
    hipMemsetAsync(deg, 0, (size_t)NN * 4, stream);

    convx_kernel<<<(NN * 64 + 255) / 256, 256, 0, stream>>>(x, xb);
    transpose_kernel<<<(512 * 512) / 256, 256, 0, stream>>>(W1, w1t);
    wcat_kernel<<<(48 * HW) / 256, 256, 0, stream>>>(W2, wct);

    count_kernel<<<(NE + 255) / 256, 256, 0, stream>>>(er, ec, cnt_row, deg, rank);
    scan1_kernel<<<SCAN_NB, 1024, 0, stream>>>(cnt_row, rowptr, bsum);
    scan2_kernel<<<1, 64, 0, stream>>>(bsum, boff);
    scan3_kernel<<<(NN + 255) / 256, 256, 0, stream>>>(rowptr, boff, deg, dinv);
    scatter_kernel<<<(NE + 255) / 256, 256, 0, stream>>>(er, ec, rowptr, rank, colss);

    gemm1_kernel<<<dim3((NN + 127) / 128, DD / 128), 256, 0, stream>>>(xb, w1t, b1, tbuf);
    spmm_kernel<<<(NN + 3) / 4, 256, 0, stream>>>(tbuf, s1b, rowptr, colss, dinv);
    spmm_kernel<<<(NN + 3) / 4, 256, 0, stream>>>(s1b, s2b, rowptr, colss, dinv);
    gemm2_kernel<<<(NN + 63) / 64, 256, 0, stream>>>(tbuf, s1b, s2b, wct, b2, out);
}